// Round 6
// baseline (108.419 us; speedup 1.0000x reference)
//
#include <hip/hip_runtime.h>

#define BATCH 8
#define CHN 128
#define HH 160
#define WW 160
#define HW (HH*WW)
#define RR 2
#define MAXOFF 5
#define NOFF 25
#define TW 32
#define TH 8
#define PW (TW + 2*RR)     /* 36 */
#define PH (TH + 2*RR)     /* 12 */
#define NG 2
#define CPG (CHN/NG)       /* 64 */
#define RC 4
#define SCH (NG*RC)        /* 8 staged channels per round */
#define ROUNDS (CPG/RC)    /* 16 */
#define NPT 128
#define NTHREADS 256
#define CHFL (PH*PW)       /* 432 */
#define STFL (SCH*CHFL)    /* 3456 */
#define NSLOT 14

__device__ __forceinline__ int reflect_idx(int i, int n) {
    if (i < 0) i = -i;
    if (i >= n) i = 2 * (n - 1) - i;
    return i;
}

// Body rr: compute round rr from BUFc using CBc; issue rr+2 -> (SVc, CBc);
// write rr+1 (in SVn) into BUFn; single barrier.
#define BODY(SVc, SVn, CBc, CBn, BUFc, BUFn, rr)                              \
  {                                                                           \
    const float2* lb = (const float2*)(BUFc) + g * RC * (CHFL / 2)            \
                     + y * (PW / 2) + xh;                                     \
    _Pragma("unroll")                                                         \
    for (int j = 0; j < RC; ++j) {                                            \
      const float2 s = CBc[j];                                                \
      const float2* t2 = lb + j * (CHFL / 2);                                 \
      _Pragma("unroll")                                                       \
      for (int dy = 0; dy < MAXOFF; ++dy) {                                   \
        const float2 w0 = t2[dy * (PW / 2) + 0];                              \
        const float2 w1 = t2[dy * (PW / 2) + 1];                              \
        const float2 w2 = t2[dy * (PW / 2) + 2];                              \
        float2* A = &acc2[dy * MAXOFF];                                       \
        A[0].x = fmaf(s.x, w0.x, A[0].x);  A[0].y = fmaf(s.y, w0.y, A[0].y);  \
        A[1].x = fmaf(s.x, w0.y, A[1].x);  A[1].y = fmaf(s.y, w1.x, A[1].y);  \
        A[2].x = fmaf(s.x, w1.x, A[2].x);  A[2].y = fmaf(s.y, w1.y, A[2].y);  \
        A[3].x = fmaf(s.x, w1.y, A[3].x);  A[3].y = fmaf(s.y, w2.x, A[3].y);  \
        A[4].x = fmaf(s.x, w2.x, A[4].x);  A[4].y = fmaf(s.y, w2.y, A[4].y);  \
      }                                                                       \
    }                                                                         \
    if ((rr) + 2 < ROUNDS) {                                                  \
      const char* base2 = c2b + (size_t)((rr) + 2) * RC * HW * 4;             \
      _Pragma("unroll")                                                       \
      for (int k = 0; k < NSLOT; ++k)                                         \
        if (tid + k * NTHREADS < STFL)                                        \
          SVc[k] = *(const float*)(base2 + boff[k]);                          \
      _Pragma("unroll")                                                       \
      for (int j = 0; j < RC; ++j)                                            \
        CBc[j] = *(const float2*)(c1p + (size_t)(((rr) + 2) * RC + j) * HW);  \
    }                                                                         \
    if ((rr) + 1 < ROUNDS) {                                                  \
      _Pragma("unroll")                                                       \
      for (int k = 0; k < NSLOT; ++k)                                         \
        if (tid + k * NTHREADS < STFL)                                        \
          (BUFn)[tid + k * NTHREADS] = SVn[k];                                \
    }                                                                         \
    __syncthreads();                                                          \
  }

__global__ __launch_bounds__(NTHREADS) void costvol_kernel(
    const float* __restrict__ c1,
    const float* __restrict__ c2,
    const float* __restrict__ pw,
    float* __restrict__ out)
{
    __shared__ float buf[2][STFL];     // 27648 B; epilogue reuses 25600 B of it

    const int tid = threadIdx.x;
    const int g  = tid >> 7;           // channel group 0..1
    const int pt = tid & (NPT - 1);    // pixel-thread 0..127
    const int xh = pt & 15;            // float2 column 0..15
    const int y  = pt >> 4;            // row 0..7

    // XCD-aware swizzle: 800 blocks = 8 XCDs x 100; XCD k gets batch image k.
    int bid = (int)blockIdx.x;
    bid = (bid & 7) * 100 + (bid >> 3);
    const int tx0 = (bid % (WW / TW)) * TW; bid /= (WW / TW);
    const int ty0 = (bid % (HH / TH)) * TH; bid /= (HH / TH);
    const int b = bid;

    // round-invariant staging byte offsets
    int boff[NSLOT];
#pragma unroll
    for (int k = 0; k < NSLOT; ++k) {
        const int idx = tid + k * NTHREADS;
        if (idx < STFL) {
            int c   = idx / CHFL;
            int rem = idx - c * CHFL;
            int ty  = rem / PW;
            int tx  = rem - ty * PW;
            int gh  = c >> 2, j = c & 3;
            int gr  = reflect_idx(ty0 - RR + ty, HH);
            int gc  = reflect_idx(tx0 - RR + tx, WW);
            boff[k] = ((gh * CPG + j) * HW + gr * WW + gc) * 4;
        } else {
            boff[k] = 0;
        }
    }

    const char*  c2b = (const char*)(c2 + (size_t)b * CHN * HW);
    const float* c1p = c1 + ((size_t)b * CHN + g * CPG) * HW
                          + (ty0 + y) * WW + tx0 + xh * 2;

    float  svA[NSLOT], svB[NSLOT];
    float2 cbA[RC], cbB[RC];

    float2 acc2[NOFF];
#pragma unroll
    for (int i = 0; i < NOFF; ++i) acc2[i] = make_float2(0.f, 0.f);

    // ---- prologue: round 0 -> svA -> buf[0]; issue round 1 -> svB ----
    {
        const char* base0 = c2b;
#pragma unroll
        for (int k = 0; k < NSLOT; ++k)
            if (tid + k * NTHREADS < STFL)
                svA[k] = *(const float*)(base0 + boff[k]);
#pragma unroll
        for (int j = 0; j < RC; ++j)
            cbA[j] = *(const float2*)(c1p + (size_t)j * HW);
#pragma unroll
        for (int k = 0; k < NSLOT; ++k)
            if (tid + k * NTHREADS < STFL)
                buf[0][tid + k * NTHREADS] = svA[k];
        const char* base1 = c2b + (size_t)RC * HW * 4;
#pragma unroll
        for (int k = 0; k < NSLOT; ++k)
            if (tid + k * NTHREADS < STFL)
                svB[k] = *(const float*)(base1 + boff[k]);
#pragma unroll
        for (int j = 0; j < RC; ++j)
            cbB[j] = *(const float2*)(c1p + (size_t)(RC + j) * HW);
        __syncthreads();               // buf[0] holds round 0
    }

    for (int r = 0; r < ROUNDS; r += 2) {
        BODY(svA, svB, cbA, cbB, buf[0], buf[1], r);
        BODY(svB, svA, cbB, cbA, buf[1], buf[0], r + 1);
    }

    // ---- cross-group reduction + scale + PReLU + store ----
    const float a = pw[0];
    const float inv_c = 1.0f / (float)CHN;
    float2* e2 = (float2*)&buf[0][0];  // 25 * 128 * 8B = 25600 B <= 27648 B

    if (g == 1) {
#pragma unroll
        for (int o = 0; o < NOFF; ++o)
            e2[o * NPT + pt] = acc2[o];
    }
    __syncthreads();
    if (g == 0) {
        float* op = out + (size_t)b * NOFF * HW + (ty0 + y) * WW + tx0 + xh * 2;
#pragma unroll
        for (int o = 0; o < NOFF; ++o) {
            float2 v1 = e2[o * NPT + pt];
            float vx = (acc2[o].x + v1.x) * inv_c;
            float vy = (acc2[o].y + v1.y) * inv_c;
            vx = (vx >= 0.f) ? vx : a * vx;
            vy = (vy >= 0.f) ? vy : a * vy;
            *(float2*)(op + (size_t)o * HW) = make_float2(vx, vy);
        }
    }
}

extern "C" void kernel_launch(void* const* d_in, const int* in_sizes, int n_in,
                              void* d_out, int out_size, void* d_ws, size_t ws_size,
                              hipStream_t stream) {
    const float* c1 = (const float*)d_in[0];
    const float* c2 = (const float*)d_in[1];
    const float* pw = (const float*)d_in[2];
    float* out = (float*)d_out;

    dim3 grid((WW / TW) * (HH / TH) * BATCH);   // 800 blocks
    dim3 block(NTHREADS);
    costvol_kernel<<<grid, block, 0, stream>>>(c1, c2, pw, out);
}

// Round 7
// 59.229 us; speedup vs baseline: 1.8305x; 1.8305x over previous
//
#include <hip/hip_runtime.h>

#define BATCH 8
#define CHN 128
#define HH 160
#define WW 160
#define HW (HH*WW)
#define RR 2
#define MAXOFF 5
#define NOFF 25
#define TW 32
#define TH 8
#define PW (TW + 2*RR)     /* 36 */
#define PH (TH + 2*RR)     /* 12 */
#define NG 2
#define CPG (CHN/NG)       /* 64 channels per group */
#define RC 4               /* channels per group per round */
#define SCH (NG*RC)        /* 8 staged channels per round */
#define ROUNDS (CPG/RC)    /* 16 */
#define NPT 128            /* float2 pixel-threads per group */
#define NTHREADS 256
#define CHFL (PH*PW)       /* 432 floats per staged channel */
#define STFL (SCH*CHFL)    /* 3456 floats staged per round */
#define NSLOT 14           /* ceil(STFL/NTHREADS) */
#define EPFL (NOFF*NPT*2)  /* 6400 floats for epilogue exchange */

__device__ __forceinline__ int reflect_idx(int i, int n) {
    if (i < 0) i = -i;
    if (i >= n) i = 2 * (n - 1) - i;
    return i;
}

__global__ __launch_bounds__(NTHREADS) void costvol_kernel(
    const float* __restrict__ c1,
    const float* __restrict__ c2,
    const float* __restrict__ pw,
    float* __restrict__ out)
{
    __shared__ float lds[EPFL];        // 25600 B (staging uses first 13824 B)

    const int tid = threadIdx.x;
    const int g  = tid >> 7;           // channel group 0..1
    const int pt = tid & (NPT - 1);    // pixel-thread 0..127
    const int xh = pt & 15;            // float2 column 0..15
    const int y  = pt >> 4;            // row 0..7

    // XCD-aware swizzle: 800 blocks = 8 XCDs x 100 tiles; XCD k owns batch
    // image k, so c2[b] (13.1 MB) + c1[b] stay L2/L3-local to one XCD.
    int bidx = (int)blockIdx.x;
    bidx = (bidx & 7) * 100 + (bidx >> 3);
    const int tx0 = (bidx % (WW / TW)) * TW; bidx /= (WW / TW);
    const int ty0 = (bidx % (HH / TH)) * TH; bidx /= (HH / TH);
    const int b = bidx;

    // ---- round-invariant staging byte offsets (14 VGPRs, computed once) ----
    int boff[NSLOT];
#pragma unroll
    for (int k = 0; k < NSLOT; ++k) {
        const int idx = tid + k * NTHREADS;
        if (idx < STFL) {
            int c   = idx / CHFL;          // staged slot 0..7
            int rem = idx - c * CHFL;
            int ty  = rem / PW;
            int tx  = rem - ty * PW;
            int gh  = c >> 2, j = c & 3;   // group-half, channel-within-round
            int gr  = reflect_idx(ty0 - RR + ty, HH);
            int gc  = reflect_idx(tx0 - RR + tx, WW);
            boff[k] = ((gh * CPG + j) * HW + gr * WW + gc) * 4;
        } else {
            boff[k] = 0;                   // dead slots (tid>=128 at k=13)
        }
    }

    const char*  c2b = (const char*)(c2 + (size_t)b * CHN * HW);
    const float* c1p = c1 + ((size_t)b * CHN + g * CPG) * HW
                          + (ty0 + y) * WW + tx0 + xh * 2;

    float  sv[NSLOT];     // staged c2 values in flight
    float2 sc[RC], sn[RC];

    auto issue_c2 = [&](int r) {
        const char* base = c2b + (size_t)r * RC * HW * 4;
#pragma unroll
        for (int k = 0; k < NSLOT; ++k)
            if (tid + k * NTHREADS < STFL)
                sv[k] = *(const float*)(base + boff[k]);
    };
    auto write_lds = [&]() {
#pragma unroll
        for (int k = 0; k < NSLOT; ++k)
            if (tid + k * NTHREADS < STFL)
                lds[tid + k * NTHREADS] = sv[k];
    };
    auto issue_c1 = [&](int r, float2* dst) {
#pragma unroll
        for (int j = 0; j < RC; ++j)
            dst[j] = *(const float2*)(c1p + (size_t)(r * RC + j) * HW);
    };

    float2 acc2[NOFF];
#pragma unroll
    for (int i = 0; i < NOFF; ++i) acc2[i] = make_float2(0.f, 0.f);

    // ---- prologue: stage round 0, prefetch round 1 ----
    issue_c2(0);
    issue_c1(0, sc);
    write_lds();
    __syncthreads();                   // lds holds round 0
    issue_c2(1);
    issue_c1(1, sn);

    for (int r = 0; r < ROUNDS; ++r) {
        // compute round r from lds + sc (overlaps round r+1's global loads)
        const float2* lbase = (const float2*)lds + g * RC * (CHFL / 2)
                            + y * (PW / 2) + xh;
#pragma unroll
        for (int j = 0; j < RC; ++j) {
            const float2 s = sc[j];
            const float2* t2 = lbase + j * (CHFL / 2);
#pragma unroll
            for (int dy = 0; dy < MAXOFF; ++dy) {
                const float2 w0 = t2[dy * (PW / 2) + 0];
                const float2 w1 = t2[dy * (PW / 2) + 1];
                const float2 w2 = t2[dy * (PW / 2) + 2];
                float2* A = &acc2[dy * MAXOFF];
                A[0].x = fmaf(s.x, w0.x, A[0].x);  A[0].y = fmaf(s.y, w0.y, A[0].y);
                A[1].x = fmaf(s.x, w0.y, A[1].x);  A[1].y = fmaf(s.y, w1.x, A[1].y);
                A[2].x = fmaf(s.x, w1.x, A[2].x);  A[2].y = fmaf(s.y, w1.y, A[2].y);
                A[3].x = fmaf(s.x, w1.y, A[3].x);  A[3].y = fmaf(s.y, w2.x, A[3].y);
                A[4].x = fmaf(s.x, w2.x, A[4].x);  A[4].y = fmaf(s.y, w2.y, A[4].y);
            }
        }
        __syncthreads();               // everyone done reading lds (round r)
        if (r + 1 < ROUNDS) {
            write_lds();               // waits on round r+1's loads, writes them
#pragma unroll
            for (int j = 0; j < RC; ++j) sc[j] = sn[j];
            __syncthreads();           // lds holds round r+1
            if (r + 2 < ROUNDS) {
                issue_c2(r + 2);       // overlap with next compute
                issue_c1(r + 2, sn);
            }
        }
    }

    // ---- cross-group reduction + scale + PReLU + store ----
    const float a = pw[0];
    const float inv_c = 1.0f / (float)CHN;

    __syncthreads();
    if (g == 1) {
        float2* e2 = (float2*)lds;
#pragma unroll
        for (int o = 0; o < NOFF; ++o)
            e2[o * NPT + pt] = acc2[o];
    }
    __syncthreads();
    if (g == 0) {
        const float2* e2 = (const float2*)lds;
        float* op = out + (size_t)b * NOFF * HW + (ty0 + y) * WW + tx0 + xh * 2;
#pragma unroll
        for (int o = 0; o < NOFF; ++o) {
            float2 v1 = e2[o * NPT + pt];
            float vx = (acc2[o].x + v1.x) * inv_c;
            float vy = (acc2[o].y + v1.y) * inv_c;
            vx = (vx >= 0.f) ? vx : a * vx;
            vy = (vy >= 0.f) ? vy : a * vy;
            *(float2*)(op + (size_t)o * HW) = make_float2(vx, vy);
        }
    }
}

extern "C" void kernel_launch(void* const* d_in, const int* in_sizes, int n_in,
                              void* d_out, int out_size, void* d_ws, size_t ws_size,
                              hipStream_t stream) {
    const float* c1 = (const float*)d_in[0];
    const float* c2 = (const float*)d_in[1];
    const float* pw = (const float*)d_in[2];
    float* out = (float*)d_out;

    dim3 grid((WW / TW) * (HH / TH) * BATCH);   // 5*20*8 = 800 blocks
    dim3 block(NTHREADS);
    costvol_kernel<<<grid, block, 0, stream>>>(c1, c2, pw, out);
}